// Round 7
// baseline (405.202 us; speedup 1.0000x reference)
//
#include <hip/hip_runtime.h>
#include <hip/hip_bf16.h>

// FlexibleGCN forward on MI355X — Round 15:
//  * gemm2 fused into agg1, fc fused into agg2: per-node row@W (64x64) done
//    in the agg kernels' latency shadow (VALUBusy was 16%). W staged in LDS
//    (16KB); row broadcast via padded per-wave LDS rowbuf (wave-coherent,
//    no syncthreads in loop). Kills 2 dispatches + h1 roundtrip (25.6MB) +
//    fc's emb re-read (25.6MB).
//  * agg gather: depth-8 (R12-proven; depth-16 was flat, R14), 2048-block
//    grid-stride.
//  * CSR: R14 structure (4 kernels, inlined bucket scans).

constexpr int IN_DIM  = 128;
constexpr int HDIM    = 64;
constexpr int NBLK_A  = 256;   // blocks in pass A (must match histg stride)
constexpr int BSH     = 8;     // bucket shift: 256 nodes per bucket
constexpr int MAXNB   = 512;   // max buckets supported (N <= 131072)
constexpr int PADSLK  = 1792;  // per-bucket esrc slack: 256 nodes x 7 max pad

__device__ __forceinline__ float bf2f(unsigned int u) {
    return __uint_as_float(u << 16);
}
__device__ __forceinline__ unsigned short f2bf_bits(float f) {
    __hip_bfloat16 b = __float2bfloat16(f);
    return *(unsigned short*)&b;
}

// ---------- CSR build ----------

__global__ void binA_count(const int* __restrict__ dst, int* __restrict__ histg,
                           int E, int NB, int chunk) {
    __shared__ int h[MAXNB];
    for (int i = threadIdx.x; i < NB; i += 256) h[i] = 0;
    __syncthreads();
    int beg = blockIdx.x * chunk;
    int end = min(E, beg + chunk);
    for (int e = beg + threadIdx.x; e < end; e += 256)
        atomicAdd(&h[dst[e] >> BSH], 1);
    __syncthreads();
    for (int i = threadIdx.x; i < NB; i += 256)
        histg[i * NBLK_A + blockIdx.x] = h[i];
}

__global__ void binA_scanblocks(int* __restrict__ histg, int* __restrict__ btot) {
    __shared__ int sm[NBLK_A];
    int tid = threadIdx.x;
    int v = histg[blockIdx.x * NBLK_A + tid];
    sm[tid] = v;
    __syncthreads();
    for (int off = 1; off < NBLK_A; off <<= 1) {
        int t = (tid >= off) ? sm[tid - off] : 0;
        __syncthreads();
        sm[tid] += t;
        __syncthreads();
    }
    histg[blockIdx.x * NBLK_A + tid] = sm[tid] - v;   // exclusive
    if (tid == NBLK_A - 1) btot[blockIdx.x] = sm[tid];
}

// In-block inclusive scan of btot[0..NB) over MAXNB entries (256 threads,
// 2 elements/thread). bb[] ends inclusive; exclusive = bb[i] - btot[i].
__device__ __forceinline__ void bucket_scan(const int* __restrict__ btot,
                                            int* bb, int NB) {
    int tid = threadIdx.x;
    for (int i = tid; i < MAXNB; i += 256) bb[i] = (i < NB) ? btot[i] : 0;
    __syncthreads();
    for (int off = 1; off < MAXNB; off <<= 1) {
        int i0 = tid, i1 = tid + 256;
        int t0 = (i0 >= off) ? bb[i0 - off] : 0;
        int t1 = (i1 >= off) ? bb[i1 - off] : 0;
        __syncthreads();
        bb[i0] += t0;
        bb[i1] += t1;
        __syncthreads();
    }
}

__global__ void binA_scatter(const int* __restrict__ src, const int* __restrict__ dst,
                             const int* __restrict__ histg, const int* __restrict__ btot,
                             int* __restrict__ staging, int E, int NB, int chunk) {
    __shared__ int bb[MAXNB];
    __shared__ int cur[MAXNB];
    bucket_scan(btot, bb, NB);
    for (int i = threadIdx.x; i < NB; i += 256)
        cur[i] = (bb[i] - btot[i]) + histg[i * NBLK_A + blockIdx.x];
    __syncthreads();
    int beg = blockIdx.x * chunk;
    int end = min(E, beg + chunk);
    for (int e = beg + threadIdx.x; e < end; e += 256) {
        int s = src[e];
        int d = dst[e];
        int pos = atomicAdd(&cur[d >> BSH], 1);
        staging[pos] = (s << BSH) | (d & 255);    // src<2^17, local dst 8 bits
    }
}

// Builds padded CSR: per-node range rounded up to a multiple of 8; pad
// slots point at node N (whose hp/hp2 rows are zeroed here).
__global__ void binB_finalize(const int* __restrict__ staging, const int* __restrict__ btot,
                              int2* __restrict__ rows, int* __restrict__ esrc,
                              float* __restrict__ dinv, unsigned int* __restrict__ hp_rowN,
                              unsigned int* __restrict__ hp2_rowN, int N, int NB) {
    __shared__ int bb[MAXNB];
    __shared__ int cnt[256], sm[256], cur[256];
    int tid = threadIdx.x;
    int b = blockIdx.x;
    bucket_scan(btot, bb, NB);
    int node0 = b << BSH;
    int nloc = min(256, N - node0);
    int eend = bb[b];
    int ebeg = eend - btot[b];
    int ebegP = ebeg + b * PADSLK;            // padded bucket base
    cnt[tid] = 0;
    __syncthreads();
    for (int e = ebeg + tid; e < eend; e += 256)
        atomicAdd(&cnt[staging[e] & 255], 1);
    __syncthreads();
    int v = cnt[tid];
    int pv = (v + 7) & ~7;                    // padded count
    sm[tid] = pv;
    __syncthreads();
    for (int off = 1; off < 256; off <<= 1) {
        int t = (tid >= off) ? sm[tid - off] : 0;
        __syncthreads();
        sm[tid] += t;
        __syncthreads();
    }
    int excl = sm[tid] - pv;                  // padded exclusive offset
    cur[tid] = excl;
    __syncthreads();
    if (tid < nloc) {
        rows[node0 + tid] = make_int2(ebegP + excl, ebegP + excl + pv);
        dinv[node0 + tid] = rsqrtf((float)v + 1.0f);   // +1 self-loop
        for (int q = v; q < pv; ++q)          // fill pad slots -> zero row
            esrc[ebegP + excl + q] = N;
    }
    if (b == 0 && tid < 32) {                 // zero gather rows N (128B each)
        hp_rowN[tid] = 0u;
        hp2_rowN[tid] = 0u;
    }
    for (int e = ebeg + tid; e < eend; e += 256) {
        int p = staging[e];
        int pos = ebegP + atomicAdd(&cur[p & 255], 1);
        esrc[pos] = p >> BSH;
    }
}

// ---------- gemm1: hp = bf16((x @ W1) * dinv) ----------

__global__ __launch_bounds__(256, 4) void gemm1_kernel(
        const float* __restrict__ X, const float* __restrict__ W,
        const float* __restrict__ dinv, unsigned short* __restrict__ Y, int n) {
    constexpr int K = IN_DIM;
    constexpr int KC = 32;
    constexpr int XSTR = 132;                 // floats
    __shared__ float Xt[KC * XSTR];           // 16.9 KB
    __shared__ float Ws[KC * 64];             // 8 KB
    const int tid = threadIdx.x;
    const int node0 = blockIdx.x * 128;
    const int r0 = (tid >> 4) * 8;            // 0..120
    const int c0 = (tid & 15) * 4;            // 0..60

    float acc[8][4];
#pragma unroll
    for (int a = 0; a < 8; ++a)
#pragma unroll
        for (int b = 0; b < 4; ++b) acc[a][b] = 0.f;

    for (int kc = 0; kc < K; kc += KC) {
        __syncthreads();
#pragma unroll
        for (int i = 0; i < 4; ++i) {
            int s = tid + i * 256;
            int row = s >> 3;
            int kq = s & 7;
            int grow = node0 + row;
            float4 v = make_float4(0.f, 0.f, 0.f, 0.f);
            if (grow < n)
                v = *(const float4*)&X[(size_t)grow * K + kc + kq * 4];
            Xt[(kq * 4 + 0) * XSTR + row] = v.x;
            Xt[(kq * 4 + 1) * XSTR + row] = v.y;
            Xt[(kq * 4 + 2) * XSTR + row] = v.z;
            Xt[(kq * 4 + 3) * XSTR + row] = v.w;
        }
#pragma unroll
        for (int i = 0; i < 2; ++i) {
            int s = tid + i * 256;
            *(float4*)&Ws[s * 4] = *(const float4*)&W[(size_t)kc * 64 + s * 4];
        }
        __syncthreads();
#pragma unroll
        for (int kk = 0; kk < KC; kk += 4) {
            float4 xa[4][2];
            float4 wv[4];
#pragma unroll
            for (int i = 0; i < 4; ++i) {
                xa[i][0] = *(const float4*)&Xt[(kk + i) * XSTR + r0];
                xa[i][1] = *(const float4*)&Xt[(kk + i) * XSTR + r0 + 4];
                wv[i]    = *(const float4*)&Ws[(kk + i) * 64 + c0];
            }
#pragma unroll
            for (int i = 0; i < 4; ++i) {
                const float* xp = (const float*)&xa[i][0];
                const float* wp = (const float*)&wv[i];
#pragma unroll
                for (int rr = 0; rr < 8; ++rr)
#pragma unroll
                    for (int cc = 0; cc < 4; ++cc)
                        acc[rr][cc] += xp[rr] * wp[cc];
            }
        }
    }
#pragma unroll
    for (int rr = 0; rr < 8; ++rr) {
        int node = node0 + r0 + rr;
        if (node < n) {
            float d = dinv[node];
            __hip_bfloat16 vb[4];
#pragma unroll
            for (int cc = 0; cc < 4; ++cc)
                vb[cc] = __float2bfloat16(acc[rr][cc] * d);
            *(uint2*)&Y[(size_t)node * 64 + c0] = *(uint2*)vb;
        }
    }
}

// ---------- fused aggregation + row-wise dense ----------
// Wave = 8 nodes x 8 lanes. Lane j holds feats 8j..8j+7 (uint4 of the 128B
// bf16 row). Depth-8 gathers; pad-to-8 tail-free. Epilogue per node:
//   o = relu(dinv*acc + bias)          (the conv output row, fp32)
//   y = o @ Wn (64x64, LDS-staged)     (row broadcast via padded LDS rowbuf)
// MODE 0 (agg1+gemm2): write hp2 = bf16(y * dinv)   [row for layer-2 gather]
// MODE 1 (agg2+fc):    write emb = o (fp32), logits = y + bfc.
template<int MODE>
__global__ __launch_bounds__(256) void agg_fused(
        const uint4* __restrict__ hp4, const int* __restrict__ esrc,
        const int2* __restrict__ rows, const float* __restrict__ dinv,
        const float* __restrict__ bias, const float* __restrict__ Wn,
        const float* __restrict__ bfc, void* __restrict__ out,
        float* __restrict__ logits, int n) {
    __shared__ float Ws[64 * 64];             // 16 KB, [f][c]
    __shared__ float rb[4][8][68];            // 8.7 KB, padded row buffer
    for (int i = threadIdx.x; i < 1024; i += 256)
        ((float4*)Ws)[i] = ((const float4*)Wn)[i];
    __syncthreads();

    const int lane = threadIdx.x & 63;
    const int j = lane & 7;
    const int g = lane >> 3;
    const int w = threadIdx.x >> 6;
    const int step = gridDim.x * 32;

    // hoisted per-lane constants
    float bb0[8];
#pragma unroll
    for (int t = 0; t < 8; ++t) bb0[t] = bias[8 * j + t];
    float bo[8];
    if (MODE == 1) {
#pragma unroll
        for (int t = 0; t < 8; ++t) bo[t] = bfc[8 * j + t];
    }

    for (int idx = blockIdx.x * 32 + w * 8 + g; idx < n; idx += step) {
        const int2 be = rows[idx];

        float acc[8];
        {   // self-loop: own row
            uint4 u = hp4[(size_t)idx * 8 + j];
            acc[0] = bf2f(u.x & 0xffff); acc[1] = bf2f(u.x >> 16);
            acc[2] = bf2f(u.y & 0xffff); acc[3] = bf2f(u.y >> 16);
            acc[4] = bf2f(u.z & 0xffff); acc[5] = bf2f(u.z >> 16);
            acc[6] = bf2f(u.w & 0xffff); acc[7] = bf2f(u.w >> 16);
        }
        for (int k = be.x; k < be.y; k += 8) {
            int s[8];
#pragma unroll
            for (int i = 0; i < 8; ++i)
                s[i] = __builtin_nontemporal_load(&esrc[k + i]);
            uint4 u[8];
#pragma unroll
            for (int i = 0; i < 8; ++i)
                u[i] = hp4[(size_t)s[i] * 8 + j];
#pragma unroll
            for (int i = 0; i < 8; ++i) {
                acc[0] += bf2f(u[i].x & 0xffff); acc[1] += bf2f(u[i].x >> 16);
                acc[2] += bf2f(u[i].y & 0xffff); acc[3] += bf2f(u[i].y >> 16);
                acc[4] += bf2f(u[i].z & 0xffff); acc[5] += bf2f(u[i].z >> 16);
                acc[6] += bf2f(u[i].w & 0xffff); acc[7] += bf2f(u[i].w >> 16);
            }
        }
        const float d = dinv[idx];
        float o[8];
#pragma unroll
        for (int t = 0; t < 8; ++t)
            o[t] = fmaxf(fmaf(d, acc[t], bb0[t]), 0.f);

        // stage row (wave-coherent; readers are this wave only)
        *(float4*)&rb[w][g][j * 8]     = make_float4(o[0], o[1], o[2], o[3]);
        *(float4*)&rb[w][g][j * 8 + 4] = make_float4(o[4], o[5], o[6], o[7]);

        float y[8] = {0.f, 0.f, 0.f, 0.f, 0.f, 0.f, 0.f, 0.f};
#pragma unroll
        for (int fw = 0; fw < 8; ++fw) {
            float4 r0 = *(const float4*)&rb[w][g][fw * 8];
            float4 r1 = *(const float4*)&rb[w][g][fw * 8 + 4];
            float rv[8] = {r0.x, r0.y, r0.z, r0.w, r1.x, r1.y, r1.z, r1.w};
#pragma unroll
            for (int e = 0; e < 8; ++e) {
                float val = rv[e];
                const float4 w0 = *(const float4*)&Ws[(fw * 8 + e) * 64 + j * 8];
                const float4 w1 = *(const float4*)&Ws[(fw * 8 + e) * 64 + j * 8 + 4];
                y[0] = fmaf(val, w0.x, y[0]); y[1] = fmaf(val, w0.y, y[1]);
                y[2] = fmaf(val, w0.z, y[2]); y[3] = fmaf(val, w0.w, y[3]);
                y[4] = fmaf(val, w1.x, y[4]); y[5] = fmaf(val, w1.y, y[5]);
                y[6] = fmaf(val, w1.z, y[6]); y[7] = fmaf(val, w1.w, y[7]);
            }
        }

        if (MODE == 0) {
            uint4 pk;
            pk.x = (unsigned)f2bf_bits(y[0] * d) | ((unsigned)f2bf_bits(y[1] * d) << 16);
            pk.y = (unsigned)f2bf_bits(y[2] * d) | ((unsigned)f2bf_bits(y[3] * d) << 16);
            pk.z = (unsigned)f2bf_bits(y[4] * d) | ((unsigned)f2bf_bits(y[5] * d) << 16);
            pk.w = (unsigned)f2bf_bits(y[6] * d) | ((unsigned)f2bf_bits(y[7] * d) << 16);
            ((uint4*)out)[(size_t)idx * 8 + j] = pk;
        } else {
            ((float4*)out)[(size_t)idx * 16 + 2 * j]     = make_float4(o[0], o[1], o[2], o[3]);
            ((float4*)out)[(size_t)idx * 16 + 2 * j + 1] = make_float4(o[4], o[5], o[6], o[7]);
            float4 l0 = make_float4(y[0] + bo[0], y[1] + bo[1], y[2] + bo[2], y[3] + bo[3]);
            float4 l1 = make_float4(y[4] + bo[4], y[5] + bo[5], y[6] + bo[6], y[7] + bo[7]);
            *(float4*)&logits[(size_t)idx * 64 + 8 * j]     = l0;
            *(float4*)&logits[(size_t)idx * 64 + 8 * j + 4] = l1;
        }
    }
}

extern "C" void kernel_launch(void* const* d_in, const int* in_sizes, int n_in,
                              void* d_out, int out_size, void* d_ws, size_t ws_size,
                              hipStream_t stream) {
    const float* x   = (const float*)d_in[0];
    const float* W1  = (const float*)d_in[1];
    const float* b1  = (const float*)d_in[2];
    const float* W2  = (const float*)d_in[3];
    const float* b2  = (const float*)d_in[4];
    const float* Wfc = (const float*)d_in[5];
    const float* bfc = (const float*)d_in[6];
    const int*  eidx = (const int*)d_in[7];

    const int N = in_sizes[0] / IN_DIM;     // 100000
    const int E = in_sizes[7] / 2;          // 1600000
    const int* src = eidx;
    const int* dst = eidx + E;

    const int NB    = (N + 255) >> BSH;     // 391 buckets
    const int chunk = (E + NBLK_A - 1) / NBLK_A;
    const int EP    = E + NB * PADSLK;      // padded esrc capacity

    // ws layout (ints, regions 16B-aligned):
    // rows[N] (int2) | dinv[N] | histg[NB*256] | btot[512]
    //   | esrc[EP] | hp[(N+1)*32] (bf16 rows, row N = zero)
    //   | hp2[(N+1)*32] (bf16 rows, row N = zero)
    // staging int[E] aliases hp (dead before gemm1 writes hp).
    int* p = (int*)d_ws;
    int2* rows = (int2*)p;           p += (size_t)2 * N + 2;
    float* dinv = (float*)p;         p += (size_t)((N + 3) & ~3);
    int* histg = p;                  p += (size_t)((NB * NBLK_A + 3) & ~3);
    int* btot = p;                   p += 512;
    int* esrc = p;                   p += (size_t)((EP + 3) & ~3);
    unsigned short* hp  = (unsigned short*)p;  p += (size_t)(N + 1) * 32;
    unsigned short* hp2 = (unsigned short*)p;  p += (size_t)(N + 1) * 32;
    int* staging = (int*)hp;                   // E ints < (N+1)*32 ints
    unsigned int* hp_rowN  = (unsigned int*)(hp  + (size_t)N * 64);
    unsigned int* hp2_rowN = (unsigned int*)(hp2 + (size_t)N * 64);

    float* emb    = (float*)d_out;
    float* logits = emb + (size_t)N * HDIM;

    // ---- CSR build (shared by both conv layers) ----
    binA_count<<<NBLK_A, 256, 0, stream>>>(dst, histg, E, NB, chunk);
    binA_scanblocks<<<NB, NBLK_A, 0, stream>>>(histg, btot);
    binA_scatter<<<NBLK_A, 256, 0, stream>>>(src, dst, histg, btot, staging, E, NB, chunk);
    binB_finalize<<<NB, 256, 0, stream>>>(staging, btot, rows, esrc, dinv,
                                          hp_rowN, hp2_rowN, N, NB);

    const int gBlocks = (N + 127) / 128;
    const int aBlocks = 2048;               // 256 CU x 8 blocks, grid-stride

    // ---- layer 1 gemm ----
    gemm1_kernel<<<gBlocks, 256, 0, stream>>>(x, W1, dinv, hp, N);

    // ---- layer 1 agg + layer 2 gemm (fused) ----
    agg_fused<0><<<aBlocks, 256, 0, stream>>>(
        (const uint4*)hp, esrc, rows, dinv, b1, W2, nullptr, hp2, nullptr, N);

    // ---- layer 2 agg + FC head (fused) ----
    agg_fused<1><<<aBlocks, 256, 0, stream>>>(
        (const uint4*)hp2, esrc, rows, dinv, b2, Wfc, bfc, emb, logits, N);
}